// Round 1
// baseline (143.023 us; speedup 1.0000x reference)
//
#include <hip/hip_runtime.h>

// Mixture-of-Tastes forward: per edge (u,v):
//   logits[m] = dot(attn_emb[u][m], movie_emb[v]);  att = softmax(logits)
//   scores[m] = dot(taste_emb[u][m], movie_emb[v])
//   y = sum_m att[m]*scores[m] + movie_bias[v] + user_bias[u]
// M=8 tastes, K=32. 32 lanes per edge, 2 edges per wave64.
// lane s in [0,32): holds flats [8s, 8s+8) of the 256-float user rows.
//   taste m = s>>2, k-chunk = 8*(s&3).

#define MOT_B 524288

__global__ __launch_bounds__(256, 4) void mot_fwd_kernel(
    const int2* __restrict__ edge,          // [B]
    const float4* __restrict__ taste_emb,   // [N_USERS][64] float4
    const float4* __restrict__ attn_emb,    // [N_USERS][64] float4
    const float4* __restrict__ movie_emb,   // [N_MOVIES][8] float4
    const float* __restrict__ user_bias,    // [N_USERS]
    const float* __restrict__ movie_bias,   // [N_MOVIES]
    float* __restrict__ out,                // [B]
    int nEdges)
{
    const int tid  = blockIdx.x * 256 + (int)threadIdx.x;
    const int wave = tid >> 6;
    const int lane = tid & 63;
    const int h    = lane >> 5;    // which edge within the wave
    const int s    = lane & 31;    // sub-lane within the edge
    const int eid  = wave * 2 + h;
    if (eid >= nEdges) return;

    const int2 ed = edge[eid];
    const int u = ed.x;
    const int v = ed.y;

    const float4* __restrict__ Ap = attn_emb  + (size_t)u * 64;
    const float4* __restrict__ Tp = taste_emb + (size_t)u * 64;
    const float4* __restrict__ Ep = movie_emb + (size_t)v * 8;

    // Row loads: lane s covers float4 indices 2s, 2s+1 (flats 8s..8s+8).
    const float4 a0 = Ap[2 * s];
    const float4 a1 = Ap[2 * s + 1];
    const float4 t0 = Tp[2 * s];
    const float4 t1 = Tp[2 * s + 1];
    const int c = s & 3;                 // k-chunk within taste
    const float4 e0 = Ep[2 * c];
    const float4 e1 = Ep[2 * c + 1];

    // Partial dots (8 elements per lane).
    float lp = a0.x * e0.x + a0.y * e0.y + a0.z * e0.z + a0.w * e0.w
             + a1.x * e1.x + a1.y * e1.y + a1.z * e1.z + a1.w * e1.w;
    float sp = t0.x * e0.x + t0.y * e0.y + t0.z * e0.z + t0.w * e0.w
             + t1.x * e1.x + t1.y * e1.y + t1.z * e1.z + t1.w * e1.w;

    // Reduce within the 4-lane taste group (lanes differing in bits 0,1).
    lp += __shfl_xor(lp, 1);
    lp += __shfl_xor(lp, 2);
    sp += __shfl_xor(sp, 1);
    sp += __shfl_xor(sp, 2);
    // Now every lane of taste-group m holds logit_m (lp) and score_m (sp).

    // Softmax across the 8 tastes (groups differ in lane bits 2,3,4).
    // Inputs are scaled by 1/K: |logit| < ~0.05, so no max-subtraction needed
    // (mathematically identical to the reference's stabilized softmax).
    const float ex = __expf(lp);
    float den = ex;
    float num = ex * sp;
    den += __shfl_xor(den, 4);
    num += __shfl_xor(num, 4);
    den += __shfl_xor(den, 8);
    num += __shfl_xor(num, 8);
    den += __shfl_xor(den, 16);
    num += __shfl_xor(num, 16);

    if (s == 0) {
        out[eid] = num / den + user_bias[u] + movie_bias[v];
    }
}

extern "C" void kernel_launch(void* const* d_in, const int* in_sizes, int n_in,
                              void* d_out, int out_size, void* d_ws, size_t ws_size,
                              hipStream_t stream) {
    const int2*   edge       = (const int2*)d_in[0];
    const float4* taste_emb  = (const float4*)d_in[1];
    const float4* attn_emb   = (const float4*)d_in[2];
    const float4* movie_emb  = (const float4*)d_in[3];
    const float*  user_bias  = (const float*)d_in[4];
    const float*  movie_bias = (const float*)d_in[5];
    float*        out        = (float*)d_out;

    const int nEdges = in_sizes[0] / 2;        // edge is [B,2] int32
    // 2 edges per wave64, 4 waves per block -> 8 edges per block.
    const int blocks = (nEdges + 7) / 8;
    mot_fwd_kernel<<<blocks, 256, 0, stream>>>(
        edge, taste_emb, attn_emb, movie_emb, user_bias, movie_bias, out, nEdges);
}